// Round 1
// baseline (674.110 us; speedup 1.0000x reference)
//
#include <hip/hip_runtime.h>

// DeepSeekV2 MoE gate, fused: router GEMM (fp32 VALU) + softmax + grouped top-k.
// T=16384 tokens, H=5120, E=160 experts, 8 groups x 20, top3 groups, top6 experts.
// Outputs (float32): [0 .. T*6)       = topk_idx as float
//                    [T*6 .. 2*T*6)   = topk_weight (= masked softmax score * 16)

#define NT   16384
#define HID  5120
#define NEXP 160
#define TM   32          // tokens per block
#define BK   64          // K tile
#define KT   (HID / BK)  // 80 K-iterations

__global__ __launch_bounds__(256)
void moe_gate_kernel(const float* __restrict__ X,
                     const float* __restrict__ W,
                     float* __restrict__ out)
{
    // GEMM staging and epilogue score buffer share LDS (48 KB total).
    __shared__ union alignas(16) SM {
        struct { float As[BK][TM]; float Bs[BK][NEXP]; } g;  // 8KB + 40KB
        float S[TM][NEXP + 4];                               // 21KB scores, padded
    } sm;

    const int tid = threadIdx.x;
    const int tx  = tid & 31;   // expert lane: experts tx + 32j, j=0..4
    const int ty  = tid >> 5;   // token group: tokens ty*4 .. ty*4+3
    const int t0  = blockIdx.x * TM;

    // staging coords: 16 k-chunks (float4) x 16 rows
    const int scK = tid & 15;   // k-chunk index
    const int srR = tid >> 4;   // row index 0..15

    float acc[4][5];
    #pragma unroll
    for (int i = 0; i < 4; ++i)
        #pragma unroll
        for (int j = 0; j < 5; ++j) acc[i][j] = 0.f;

    const float* xrow0 = X + (size_t)(t0 + srR) * HID;
    const float* xrow1 = X + (size_t)(t0 + srR + 16) * HID;

    for (int kt = 0; kt < KT; ++kt) {
        const int k0 = kt * BK;

        // ---- global loads into registers (before barrier) ----
        float4 xa = *(const float4*)(xrow0 + k0 + 4 * scK);
        float4 xb = *(const float4*)(xrow1 + k0 + 4 * scK);
        float4 wv[10];
        #pragma unroll
        for (int q = 0; q < 10; ++q)
            wv[q] = *(const float4*)(W + (size_t)(srR + 16 * q) * HID + k0 + 4 * scK);

        __syncthreads();  // previous tile's LDS reads done

        // ---- As[k][t] (transposed) ----
        #pragma unroll
        for (int q = 0; q < 4; ++q) {
            sm.g.As[4 * scK + q][srR]      = ((const float*)&xa)[q];
            sm.g.As[4 * scK + q][srR + 16] = ((const float*)&xb)[q];
        }
        // ---- Bs[k][e] (transposed), column XOR-swizzled within 32-groups ----
        #pragma unroll
        for (int q = 0; q < 10; ++q) {
            const int e = srR + 16 * q;
            #pragma unroll
            for (int p = 0; p < 4; ++p) {
                const int kk = 4 * scK + p;
                sm.g.Bs[kk][(e & 0xE0) | ((e ^ kk) & 31)] = ((const float*)&wv[q])[p];
            }
        }
        __syncthreads();

        // ---- compute: per-tile partial accumulators (better fp accuracy + ILP) ----
        float tacc[4][5];
        #pragma unroll
        for (int i = 0; i < 4; ++i)
            #pragma unroll
            for (int j = 0; j < 5; ++j) tacc[i][j] = 0.f;

        #pragma unroll 8
        for (int kk = 0; kk < BK; ++kk) {
            const float4 a = *(const float4*)&sm.g.As[kk][ty * 4];
            const float* bp = &sm.g.Bs[kk][(tx ^ kk) & 31];   // swizzle-matched, conflict-free
            const float b0 = bp[0], b1 = bp[32], b2 = bp[64], b3 = bp[96], b4 = bp[128];
            const float av[4] = {a.x, a.y, a.z, a.w};
            const float bv[5] = {b0, b1, b2, b3, b4};
            #pragma unroll
            for (int i = 0; i < 4; ++i)
                #pragma unroll
                for (int j = 0; j < 5; ++j)
                    tacc[i][j] = fmaf(av[i], bv[j], tacc[i][j]);
        }
        #pragma unroll
        for (int i = 0; i < 4; ++i)
            #pragma unroll
            for (int j = 0; j < 5; ++j) acc[i][j] += tacc[i][j];
    }

    // ---- write logits to LDS score buffer (overlays GEMM staging) ----
    __syncthreads();
    #pragma unroll
    for (int i = 0; i < 4; ++i)
        #pragma unroll
        for (int j = 0; j < 5; ++j)
            sm.S[ty * 4 + i][tx + 32 * j] = acc[i][j];
    __syncthreads();

    // ---- epilogue: each wave owns 8 tokens (rows disjoint across waves) ----
    const int lane = tid & 63;
    const int wv_  = tid >> 6;

    for (int it = 0; it < 8; ++it) {
        const int t = wv_ * 8 + it;

        float s0 = sm.S[t][lane];
        float s1 = sm.S[t][lane + 64];
        float s2 = (lane < 32) ? sm.S[t][lane + 128] : -3.0e38f;

        float m = fmaxf(fmaxf(s0, s1), s2);
        #pragma unroll
        for (int d = 32; d >= 1; d >>= 1) m = fmaxf(m, __shfl_xor(m, d));

        float p0 = __expf(s0 - m);
        float p1 = __expf(s1 - m);
        float p2 = (lane < 32) ? __expf(s2 - m) : 0.f;
        float sum = p0 + p1 + p2;
        #pragma unroll
        for (int d = 32; d >= 1; d >>= 1) sum += __shfl_xor(sum, d);
        const float inv = 1.0f / sum;
        const float sc0 = p0 * inv, sc1 = p1 * inv, sc2 = p2 * inv;

        sm.S[t][lane]      = sc0;
        sm.S[t][lane + 64] = sc1;
        if (lane < 32) sm.S[t][lane + 128] = sc2;
        __syncthreads();   // uniform across block (all waves loop 8x)

        // group max: lanes 0..7 each scan one group of 20
        float gm = -1.0f;
        if (lane < 8) {
            #pragma unroll
            for (int u = 0; u < 20; ++u) gm = fmaxf(gm, sm.S[t][lane * 20 + u]);
        }
        // top-3 groups (tie -> lower group index), computed redundantly on all lanes
        unsigned gmask = 0u;
        {
            float gv[8];
            #pragma unroll
            for (int g = 0; g < 8; ++g) gv[g] = __shfl(gm, g);
            #pragma unroll
            for (int r = 0; r < 3; ++r) {
                int bi = 0; float bv2 = -2.0f;
                #pragma unroll
                for (int g = 0; g < 8; ++g) {
                    const bool taken = (gmask >> g) & 1u;
                    if (!taken && gv[g] > bv2) { bv2 = gv[g]; bi = g; }
                }
                gmask |= (1u << bi);
            }
        }

        // masked candidates (reference: non-selected groups -> 0.0)
        float v0 = ((gmask >> (lane / 20)) & 1u) ? sc0 : 0.f;
        float v1 = ((gmask >> ((lane + 64) / 20)) & 1u) ? sc1 : 0.f;
        float v2 = (lane < 32) ? ((((gmask >> ((lane + 128) / 20)) & 1u) ? sc2 : 0.f))
                               : -1.f;

        // 6 rounds of wave-wide argmax (value desc, tie -> lower expert index)
        float oIdx = 0.f, oW = 0.f;
        #pragma unroll
        for (int r = 0; r < 6; ++r) {
            float bv = v0; int bi = lane;
            if (v1 > bv) { bv = v1; bi = lane + 64; }
            if (v2 > bv) { bv = v2; bi = lane + 128; }
            #pragma unroll
            for (int d = 1; d < 64; d <<= 1) {
                const float ov = __shfl_xor(bv, d);
                const int   oi = __shfl_xor(bi, d);
                if (ov > bv || (ov == bv && oi < bi)) { bv = ov; bi = oi; }
            }
            if (lane == r) { oIdx = (float)bi; oW = bv * 16.0f; }
            if (bi == lane)            v0 = -1.f;
            else if (bi == lane + 64)  v1 = -1.f;
            else if (bi == lane + 128) v2 = -1.f;
        }

        const int tg = t0 + t;
        if (lane < 6) {
            out[(size_t)tg * 6 + lane]                    = oIdx;
            out[(size_t)NT * 6 + (size_t)tg * 6 + lane]   = oW;
        }
        __syncthreads();
    }
}

extern "C" void kernel_launch(void* const* d_in, const int* in_sizes, int n_in,
                              void* d_out, int out_size, void* d_ws, size_t ws_size,
                              hipStream_t stream)
{
    const float* X = (const float*)d_in[0];   // [4,4096,5120] fp32
    const float* W = (const float*)d_in[1];   // [160,5120] fp32
    float* out = (float*)d_out;               // [T*6 idx][T*6 weight] fp32

    dim3 grid(NT / TM);   // 512 blocks
    dim3 block(256);
    moe_gate_kernel<<<grid, block, 0, stream>>>(X, W, out);
}

// Round 5
// 549.142 us; speedup vs baseline: 1.2276x; 1.2276x over previous
//
#include <hip/hip_runtime.h>

// DeepSeekV2 MoE gate — fp32 VALU GEMM, BIT-IDENTICAL arithmetic to the
// passing round-1 kernel (per (t,e): 80 K-tiles of 64 sequential fmafs,
// tile partials accumulated in order), restructured for throughput:
//   - 64-token blocks, per-thread tile 8 tokens x 5 experts (40 FMA/kk)
//   - aligned ds_read_b128 operand reads, constant strides (offset-folded)
//   - depth-3 software pipeline over kk, global prefetch 1 K-tile ahead
// Epilogue (softmax + grouped top-3/top-6) is round-1's code verbatim.
// Outputs (float32): [0..T*6) = topk_idx as float, [T*6..2*T*6) = weight.

#define NT    16384
#define HID   5120
#define NEXP  160
#define TOKB  64               // tokens per block
#define NKT   80               // K tiles of 64
#define AS_S  76               // As row stride (floats): [64 kk][76]
#define B4_S  132              // B4 row stride: [64 kk][132] experts 0..127
#define B1_S  36               // B1 row stride: [64 kk][36]  experts 128..159
#define S_S   164              // epilogue score row stride

__global__ __launch_bounds__(256)
void moe_gate_kernel(const float* __restrict__ X,
                     const float* __restrict__ W,
                     float* __restrict__ out)
{
    // GEMM staging and epilogue scores share LDS (62464 B).
    __shared__ union alignas(16) SM {
        struct { float As[64 * AS_S]; float B4[64 * B4_S]; float B1[64 * B1_S]; } g;
        float S[TOKB * S_S];
    } u;

    const int tid = threadIdx.x;
    const int tx  = tid & 31;      // expert group: {4tx..4tx+3, 128+tx}
    const int oct = tid >> 5;      // token octet: tokens 8*oct..8*oct+7
    const int sr  = tid >> 2;      // staging row 0..63
    const int scq = tid & 3;       // staging col quad
    const int tb  = blockIdx.x * TOKB;

    float acc[8][5];
    #pragma unroll
    for (int i = 0; i < 8; ++i)
        #pragma unroll
        for (int q = 0; q < 5; ++q) acc[i][q] = 0.f;

    float4 xst[4];                 // X staging: row sr, 16 floats
    float4 wst[12];                // W staging: rows sr,sr+64,(sr+128), 16 floats each

    const float* xrow = X + (size_t)(tb + sr) * HID + 4 * scq;

    auto LOADX = [&](int kt) {
        const float* xp = xrow + kt * 64;
        #pragma unroll
        for (int i = 0; i < 4; ++i) xst[i] = *(const float4*)(xp + 16 * i);
    };
    auto LOADW = [&](int kt) {
        #pragma unroll
        for (int i = 0; i < 3; ++i) {
            const int e = sr + 64 * i;
            if (e < NEXP) {
                const float* wp = W + (size_t)e * HID + kt * 64 + 4 * scq;
                #pragma unroll
                for (int j = 0; j < 4; ++j)
                    wst[4 * i + j] = *(const float4*)(wp + 16 * j);
            }
        }
    };
    auto STORE = [&]() {
        #pragma unroll
        for (int i = 0; i < 4; ++i)
            #pragma unroll
            for (int j = 0; j < 4; ++j)
                u.g.As[(4 * scq + 16 * i + j) * AS_S + sr] = ((const float*)&xst[i])[j];
        #pragma unroll
        for (int i = 0; i < 3; ++i) {
            const int e = sr + 64 * i;
            if (e < NEXP) {
                #pragma unroll
                for (int j = 0; j < 4; ++j)
                    #pragma unroll
                    for (int p = 0; p < 4; ++p) {
                        const int c = 4 * scq + 16 * j + p;
                        const float v = ((const float*)&wst[4 * i + j])[p];
                        if (e < 128) u.g.B4[c * B4_S + e] = v;
                        else         u.g.B1[c * B1_S + (e - 128)] = v;
                    }
            }
        }
    };

    float a_pre[4][8], b_pre[4][5];    // depth-3 pipeline (4 slots), static idx
    auto LOADSET = [&](int s, int kk) {
        float4 a0 = *(const float4*)&u.g.As[kk * AS_S + 8 * oct];
        float4 a1 = *(const float4*)&u.g.As[kk * AS_S + 8 * oct + 4];
        a_pre[s][0] = a0.x; a_pre[s][1] = a0.y; a_pre[s][2] = a0.z; a_pre[s][3] = a0.w;
        a_pre[s][4] = a1.x; a_pre[s][5] = a1.y; a_pre[s][6] = a1.z; a_pre[s][7] = a1.w;
        float4 b0 = *(const float4*)&u.g.B4[kk * B4_S + 4 * tx];
        b_pre[s][0] = b0.x; b_pre[s][1] = b0.y; b_pre[s][2] = b0.z; b_pre[s][3] = b0.w;
        b_pre[s][4] = u.g.B1[kk * B1_S + tx];
    };

    LOADX(0); LOADW(0);

    for (int kt = 0; kt < NKT; ++kt) {
        __syncthreads();               // prev tile's LDS reads done
        STORE();
        __syncthreads();               // tile ready
        if (kt + 1 < NKT) { LOADX(kt + 1); LOADW(kt + 1); }   // global prefetch

        float tacc[8][5];
        #pragma unroll
        for (int i = 0; i < 8; ++i)
            #pragma unroll
            for (int q = 0; q < 5; ++q) tacc[i][q] = 0.f;

        LOADSET(0, 0); LOADSET(1, 1); LOADSET(2, 2);
        #pragma unroll
        for (int kk = 0; kk < 64; ++kk) {
            if (kk + 3 < 64) LOADSET((kk + 3) & 3, kk + 3);
            const int s = kk & 3;
            #pragma unroll
            for (int i = 0; i < 8; ++i)
                #pragma unroll
                for (int q = 0; q < 5; ++q)
                    tacc[i][q] = fmaf(a_pre[s][i], b_pre[s][q], tacc[i][q]);
        }
        #pragma unroll
        for (int i = 0; i < 8; ++i)
            #pragma unroll
            for (int q = 0; q < 5; ++q) acc[i][q] += tacc[i][q];
    }

    // ---- write logits to the score buffer ----
    __syncthreads();
    #pragma unroll
    for (int i = 0; i < 8; ++i) {
        const int t = 8 * oct + i;
        #pragma unroll
        for (int q = 0; q < 4; ++q) u.S[t * S_S + 4 * tx + q] = acc[i][q];
        u.S[t * S_S + 128 + tx] = acc[i][4];
    }
    __syncthreads();

    // ---- epilogue (round-1 verified): each wave owns 16 tokens ----
    const int lane = tid & 63;
    const int wv_  = tid >> 6;

    for (int it = 0; it < 16; ++it) {
        const int t = wv_ * 16 + it;

        float s0 = u.S[t * S_S + lane];
        float s1 = u.S[t * S_S + lane + 64];
        float s2 = (lane < 32) ? u.S[t * S_S + lane + 128] : -3.0e38f;

        float m = fmaxf(fmaxf(s0, s1), s2);
        #pragma unroll
        for (int d = 32; d >= 1; d >>= 1) m = fmaxf(m, __shfl_xor(m, d));

        float p0 = __expf(s0 - m);
        float p1 = __expf(s1 - m);
        float p2 = (lane < 32) ? __expf(s2 - m) : 0.f;
        float sum = p0 + p1 + p2;
        #pragma unroll
        for (int d = 32; d >= 1; d >>= 1) sum += __shfl_xor(sum, d);
        const float inv = 1.0f / sum;
        const float sc0 = p0 * inv, sc1 = p1 * inv, sc2 = p2 * inv;

        u.S[t * S_S + lane]      = sc0;
        u.S[t * S_S + lane + 64] = sc1;
        if (lane < 32) u.S[t * S_S + lane + 128] = sc2;
        __syncthreads();   // uniform across block (all waves loop 16x)

        float gm = -1.0f;
        if (lane < 8) {
            #pragma unroll
            for (int q = 0; q < 20; ++q) gm = fmaxf(gm, u.S[t * S_S + lane * 20 + q]);
        }
        unsigned gmask = 0u;
        {
            float gv[8];
            #pragma unroll
            for (int g = 0; g < 8; ++g) gv[g] = __shfl(gm, g);
            #pragma unroll
            for (int r = 0; r < 3; ++r) {
                int bi = 0; float bv2 = -2.0f;
                #pragma unroll
                for (int g = 0; g < 8; ++g) {
                    const bool taken = (gmask >> g) & 1u;
                    if (!taken && gv[g] > bv2) { bv2 = gv[g]; bi = g; }
                }
                gmask |= (1u << bi);
            }
        }

        float v0 = ((gmask >> (lane / 20)) & 1u) ? sc0 : 0.f;
        float v1 = ((gmask >> ((lane + 64) / 20)) & 1u) ? sc1 : 0.f;
        float v2 = (lane < 32) ? ((((gmask >> ((lane + 128) / 20)) & 1u) ? sc2 : 0.f))
                               : -1.f;

        float oIdx = 0.f, oW = 0.f;
        #pragma unroll
        for (int r = 0; r < 6; ++r) {
            float bv = v0; int bi = lane;
            if (v1 > bv) { bv = v1; bi = lane + 64; }
            if (v2 > bv) { bv = v2; bi = lane + 128; }
            #pragma unroll
            for (int d = 1; d < 64; d <<= 1) {
                const float ov = __shfl_xor(bv, d);
                const int   oi = __shfl_xor(bi, d);
                if (ov > bv || (ov == bv && oi < bi)) { bv = ov; bi = oi; }
            }
            if (lane == r) { oIdx = (float)bi; oW = bv * 16.0f; }
            if (bi == lane)            v0 = -1.f;
            else if (bi == lane + 64)  v1 = -1.f;
            else if (bi == lane + 128) v2 = -1.f;
        }

        const int tg = tb + t;
        if (lane < 6) {
            out[(size_t)tg * 6 + lane]                  = oIdx;
            out[(size_t)NT * 6 + (size_t)tg * 6 + lane] = oW;
        }
        __syncthreads();
    }
}

extern "C" void kernel_launch(void* const* d_in, const int* in_sizes, int n_in,
                              void* d_out, int out_size, void* d_ws, size_t ws_size,
                              hipStream_t stream)
{
    const float* X = (const float*)d_in[0];   // [4,4096,5120] fp32
    const float* W = (const float*)d_in[1];   // [160,5120] fp32
    float* out = (float*)d_out;               // [T*6 idx][T*6 weight] fp32

    moe_gate_kernel<<<NT / TOKB, 256, 0, stream>>>(X, W, out);
}